// Round 15
// baseline (138.151 us; speedup 1.0000x reference)
//
#include <hip/hip_runtime.h>

#define NS   16
#define NV   4
#define FEAT 48          // N_EDGE_FEAT
#define WN   320         // W_NUMEL
#define MSG  28          // logical message width (fp32 out)
#define MSGB 32          // bf16 msg row stride (elements) -> 64 B rows

typedef __bf16 bf16x8 __attribute__((ext_vector_type(8)));
typedef __bf16 bf16x4 __attribute__((ext_vector_type(4)));
typedef float  f32x4  __attribute__((ext_vector_type(4)));

#define PK1_ELEMS (2 * 3 * 64 * 8)    // 3072 bf16
#define PK2_ELEMS (2 * 20 * 64 * 8)   // 20480 bf16
#define PACK_BLOCKS 8

// ---------------- prep: weight packing (blocks 0..7) + src histogram ----------------
// Swapped-operand A-frag packing (W^T), two 16-feat K-blocks per K=32 frag:
// frag (p, nt): lane l (q=l>>4, r=l&15), elem j:
//   p==0: j<4 -> k=4q+j        ; j>=4 -> k=16+4q+(j-4)
//   p==1: j<4 -> k=32+4q+j     ; j>=4 -> bias row (k==48) at (q==0,j==4), else 0
// value = W[k][col=16nt+r]  (bias slot = b[col])
__global__ void prep_kernel(const float* __restrict__ fc1_w, const float* __restrict__ fc1_b,
                            const float* __restrict__ fc2_w, const float* __restrict__ fc2_b,
                            const int* __restrict__ src,
                            __bf16* __restrict__ pk1, __bf16* __restrict__ pk2,
                            int* __restrict__ count, int E)
{
    const int tid = threadIdx.x;
    if (blockIdx.x < PACK_BLOCKS) {
        const int idx = blockIdx.x * 256 + tid;
        const int stride = PACK_BLOCKS * 256;
        for (int i = idx; i < PK1_ELEMS; i += stride) {
            const int j = i & 7, l = (i >> 3) & 63, f = i >> 9;   // f = p*3 + nt
            const int nt = f % 3, p = f / 3;
            const int q = l >> 4, col = 16 * nt + (l & 15);
            float v;
            if (p == 0) {
                const int k = (j < 4) ? (4 * q + j) : (16 + 4 * q + j - 4);
                v = fc1_w[k * FEAT + col];
            } else if (j < 4) {
                v = fc1_w[(32 + 4 * q + j) * FEAT + col];
            } else {
                v = (j == 4 && q == 0) ? fc1_b[col] : 0.f;
            }
            pk1[i] = (__bf16)v;
        }
        for (int i = idx; i < PK2_ELEMS; i += stride) {
            const int j = i & 7, l = (i >> 3) & 63, f = i >> 9;   // f = p*20 + nt
            const int nt = f % 20, p = f / 20;
            const int q = l >> 4, col = 16 * nt + (l & 15);
            float v;
            if (p == 0) {
                const int k = (j < 4) ? (4 * q + j) : (16 + 4 * q + j - 4);
                v = fc2_w[k * WN + col];
            } else if (j < 4) {
                v = fc2_w[(32 + 4 * q + j) * WN + col];
            } else {
                v = (j == 4 && q == 0) ? fc2_b[col] : 0.f;
            }
            pk2[i] = (__bf16)v;
        }
    } else {
        const int nb = gridDim.x - PACK_BLOCKS;
        for (int e = (blockIdx.x - PACK_BLOCKS) * 256 + tid; e < E; e += nb * 256)
            atomicAdd(&count[src[e]], 1);
    }
}

// ---------------- CSR scan ----------------
__global__ void scan_block(const int* __restrict__ in, int* __restrict__ outExcl,
                           int* __restrict__ bsum, int n)
{
    __shared__ int s[256];
    const int tid = threadIdx.x;
    const int i = blockIdx.x * 256 + tid;
    int v = (i < n) ? in[i] : 0;
    int acc = v;
    s[tid] = acc;
    __syncthreads();
    #pragma unroll
    for (int off = 1; off < 256; off <<= 1) {
        int t = (tid >= off) ? s[tid - off] : 0;
        __syncthreads();
        acc += t;
        s[tid] = acc;
        __syncthreads();
    }
    if (i < n) outExcl[i] = acc - v;
    if (tid == 255) bsum[blockIdx.x] = acc;
}

// ---------------- fused edge compute: swapped-operand MFMA + late CSR-rank atomic ----------------
// r12 structure. Change: the rank atomicAdd (slow L2 RMW with return) is SUNK to after
// the fc2 loop. vmcnt decrements in order, so an early-issued atomic poisons every
// later load's s_waitcnt (gather + 40 fc2 weight loads all wait >= atomic latency) —
// the r7->r9 +16us edge regression. base/boff are loaded early (fast), summed late.
// x in wave-private LDS (r6 lesson). (256,7): 36 VGPR, no spill (r12-verified).
// MODE 0: write bf16 msg row at rank. MODE 1: fp32 atomics into out + cnt.
template<int MODE>
__global__ __launch_bounds__(256, 7) void edge_mfma_kernel(
    const float* __restrict__ node_attr,
    const float* __restrict__ edge_attr,
    const float* __restrict__ edge_sh,
    const int*   __restrict__ edge_index,
    const int*   __restrict__ base,    // MODE 0
    const int*   __restrict__ boff,    // MODE 0
    int*         __restrict__ cursor,  // MODE 0
    const __bf16* __restrict__ pk1,
    const __bf16* __restrict__ pk2,
    __bf16* __restrict__ msg,      // MODE 0
    float*  __restrict__ out_acc,  // MODE 1
    float*  __restrict__ cnt,      // MODE 1
    int E)
{
    __shared__ float sX[4][32][20];    // wave-private; row stride 80 B (16B-aligned)

    const int tid = threadIdx.x;
    const int w   = tid >> 6;
    const int l   = tid & 63;
    const int q   = l >> 4;
    const int r16 = l & 15;
    const int e0  = (blockIdx.x * 4 + w) * 32;    // 32 edges per wave (2 tiles)

    const float4 z4 = make_float4(0.f, 0.f, 0.f, 0.f);
    const float bias1 = (q == 0) ? 1.f : 0.f;

    // fc1 weight frags (register-resident, shared by both tiles)
    bf16x8 w1f[2][3];
    #pragma unroll
    for (int p = 0; p < 2; ++p)
        #pragma unroll
        for (int nt = 0; nt < 3; ++nt)
            w1f[p][nt] = *reinterpret_cast<const bf16x8*>(pk1 + ((size_t)(p * 3 + nt) * 64 + l) * 8);

    // ---- gather ea B-frags (lane supplies feats 4q+j of edge r16); x -> LDS ----
    bf16x8 eaf[2][2];
    int   srcI[2], bA[2], bB[2];
    bool  evt[2];
    float sh0[2], sh1[2];
    #pragma unroll
    for (int t = 0; t < 2; ++t) {
        const int e = e0 + 16 * t + r16;
        const bool ev = (e < E);
        evt[t] = ev;
        srcI[t] = ev ? edge_index[e] : 0;
        const int dstI = ev ? edge_index[E + e] : 0;

        // CSR base pieces loaded EARLY (plain fast loads); atomic deferred to after fc2
        bA[t] = 0; bB[t] = 0;
        if (MODE == 0 && q == 0 && ev) {
            const int s = srcI[t];
            bA[t] = base[s];
            bB[t] = boff[s >> 8];
        }

        float4 ea4 = z4, sa4 = z4, da4 = z4;
        if (ev) {
            ea4 = *reinterpret_cast<const float4*>(edge_attr + (size_t)e * NS + 4 * q);
            sa4 = *reinterpret_cast<const float4*>(node_attr + (size_t)srcI[t] * NS + 4 * q);
            da4 = *reinterpret_cast<const float4*>(node_attr + (size_t)dstI * NS + 4 * q);
        }
        // lane (q, r16) owns x[4q..4q+3] of edge 16t+r16 -> one b128 LDS write
        *reinterpret_cast<f32x4*>(&sX[w][16 * t + r16][4 * q]) =
            f32x4{da4.x, da4.y, da4.z, da4.w};

        bf16x8 f0, f1;
        f0[0]=(__bf16)ea4.x; f0[1]=(__bf16)ea4.y; f0[2]=(__bf16)ea4.z; f0[3]=(__bf16)ea4.w;
        f0[4]=(__bf16)sa4.x; f0[5]=(__bf16)sa4.y; f0[6]=(__bf16)sa4.z; f0[7]=(__bf16)sa4.w;
        f1[0]=(__bf16)da4.x; f1[1]=(__bf16)da4.y; f1[2]=(__bf16)da4.z; f1[3]=(__bf16)da4.w;
        f1[4]=(__bf16)bias1; f1[5]=(__bf16)0.f; f1[6]=(__bf16)0.f; f1[7]=(__bf16)0.f;
        eaf[t][0] = f0;
        eaf[t][1] = f1;
        sh0[t] = ev ? edge_sh[(size_t)e * 9] : 0.f;
        sh1[t] = (ev && q < 3) ? edge_sh[(size_t)e * 9 + 1 + q] : 0.f;
    }

    // ---- fc1 (swapped): D[row=feat 16nt+4q+g][col=edge r16]; relu; repack to hc frags ----
    bf16x8 hc[2][2];
    #pragma unroll
    for (int t = 0; t < 2; ++t) {
        f32x4 h0 = {0.f,0.f,0.f,0.f}, h1 = {0.f,0.f,0.f,0.f}, h2 = {0.f,0.f,0.f,0.f};
        h0 = __builtin_amdgcn_mfma_f32_16x16x32_bf16(w1f[0][0], eaf[t][0], h0, 0, 0, 0);
        h0 = __builtin_amdgcn_mfma_f32_16x16x32_bf16(w1f[1][0], eaf[t][1], h0, 0, 0, 0);
        h1 = __builtin_amdgcn_mfma_f32_16x16x32_bf16(w1f[0][1], eaf[t][0], h1, 0, 0, 0);
        h1 = __builtin_amdgcn_mfma_f32_16x16x32_bf16(w1f[1][1], eaf[t][1], h1, 0, 0, 0);
        h2 = __builtin_amdgcn_mfma_f32_16x16x32_bf16(w1f[0][2], eaf[t][0], h2, 0, 0, 0);
        h2 = __builtin_amdgcn_mfma_f32_16x16x32_bf16(w1f[1][2], eaf[t][1], h2, 0, 0, 0);
        bf16x8 c0, c1;
        #pragma unroll
        for (int g = 0; g < 4; ++g) {
            c0[g]     = (__bf16)fmaxf(h0[g], 0.f);   // feats  4q+g   (nt=0)
            c0[4 + g] = (__bf16)fmaxf(h1[g], 0.f);   // feats 16+4q+g (nt=1)
            c1[g]     = (__bf16)fmaxf(h2[g], 0.f);   // feats 32+4q+g (nt=2)
        }
        c1[4] = (__bf16)bias1;                       // k=48 constant-1 (bias row)
        c1[5] = (__bf16)0.f; c1[6] = (__bf16)0.f; c1[7] = (__bf16)0.f;
        hc[t][0] = c0;
        hc[t][1] = c1;
    }

    // ---- fc2 (swapped) + fused tensor product (x from wave-private LDS) ----
    f32x4 acc0[2] = {{0.f,0.f,0.f,0.f},{0.f,0.f,0.f,0.f}};
    f32x4 acc1[2] = {{0.f,0.f,0.f,0.f},{0.f,0.f,0.f,0.f}};
    #pragma unroll 4
    for (int nt2 = 0; nt2 < 20; ++nt2) {
        const bf16x8 wf0 = *reinterpret_cast<const bf16x8*>(pk2 + ((size_t)(0 * 20 + nt2) * 64 + l) * 8);
        const bf16x8 wf1 = *reinterpret_cast<const bf16x8*>(pk2 + ((size_t)(1 * 20 + nt2) * 64 + l) * 8);
        #pragma unroll
        for (int t = 0; t < 2; ++t) {
            f32x4 d = {0.f,0.f,0.f,0.f};
            d = __builtin_amdgcn_mfma_f32_16x16x32_bf16(wf0, hc[t][0], d, 0, 0, 0);
            d = __builtin_amdgcn_mfma_f32_16x16x32_bf16(wf1, hc[t][1], d, 0, 0, 0);
            // lane holds w[edge r16][wcol = 16*nt2 + 4q+g]
            if (nt2 < 16) {
                // w0[u=nt2][c=4q+g]
                const float xv = sX[w][16 * t + r16][nt2];
                #pragma unroll
                for (int g = 0; g < 4; ++g) acc0[t][g] = fmaf(xv, d[g], acc0[t][g]);
            } else {
                // w1[u=4*(nt2-16)+q][v=g]
                const float xu = sX[w][16 * t + r16][4 * (nt2 - 16) + q];
                #pragma unroll
                for (int g = 0; g < 4; ++g) acc1[t][g] = fmaf(xu, d[g], acc1[t][g]);
            }
        }
    }

    // ---- rank atomic NOW (after all fc2 loads issued; nothing left to poison) ----
    int rnkQ[2];
    #pragma unroll
    for (int t = 0; t < 2; ++t) {
        rnkQ[t] = 0;
        if (MODE == 0 && q == 0 && evt[t])
            rnkQ[t] = bA[t] + bB[t] + atomicAdd(&cursor[srcI[t]], 1);
    }

    const float inv = 0.25f;   // 1/sqrt(16)

    // out1: reduce partial u-sums across the 4 q-groups (lane bits 4,5)
    #pragma unroll
    for (int t = 0; t < 2; ++t)
        #pragma unroll
        for (int g = 0; g < 4; ++g) {
            float s = acc1[t][g];
            s += __shfl_xor(s, 16);
            s += __shfl_xor(s, 32);
            acc1[t][g] = s;
        }

    #pragma unroll
    for (int t = 0; t < 2; ++t) {
        const int e = e0 + 16 * t + r16;
        if (e >= E) continue;
        if (MODE == 0) {
            const int rnk = __shfl(rnkQ[t], r16);      // broadcast q==0 lanes' rank
            const size_t mb = (size_t)rnk * MSGB;
            bf16x4 v4;
            #pragma unroll
            for (int g = 0; g < 4; ++g) v4[g] = (__bf16)(inv * sh0[t] * acc0[t][g]);
            *reinterpret_cast<bf16x4*>(msg + mb + 4 * q) = v4;                 // cols 4q..4q+3
            if (q < 3) {
                #pragma unroll
                for (int g = 0; g < 4; ++g)
                    msg[mb + 16 + 3 * g + q] =
                        (__bf16)(inv * sh1[t] * acc1[t][g]);                   // m=q, v=g
            }
        } else {
            const size_t ob = (size_t)srcI[t] * MSG;
            #pragma unroll
            for (int g = 0; g < 4; ++g)
                atomicAdd(&out_acc[ob + 4 * q + g], inv * sh0[t] * acc0[t][g]);
            if (q < 3) {
                #pragma unroll
                for (int g = 0; g < 4; ++g)
                    atomicAdd(&out_acc[ob + 16 + 3 * g + q], inv * sh1[t] * acc1[t][g]);
            }
            if (q == 3) atomicAdd(&cnt[srcI[t]], 1.f);
        }
    }
}

// ---------------- node gather-reduce: one wave per node, 2 rows x 32 lanes per step ----------------
__global__ __launch_bounds__(256) void node_reduce(
    const __bf16* __restrict__ msg,
    const int* __restrict__ count,
    const int* __restrict__ base,
    const int* __restrict__ boff,
    float* __restrict__ out, int N)
{
    const int tid = threadIdx.x;
    const int w   = tid >> 6;
    const int l   = tid & 63;
    const int r   = l >> 5;        // row slot 0/1
    const int c   = l & 31;
    const int n   = blockIdx.x * 4 + w;
    if (n >= N) return;

    const int deg = count[n];
    const size_t b = (size_t)(base[n] + boff[n >> 8]) * MSGB;
    float acc = 0.f;
    int j = 0;
    for (; j + 8 <= deg; j += 8) {
        float v0 = 0.f, v1 = 0.f, v2 = 0.f, v3 = 0.f;
        if (c < MSG) {
            v0 = (float)msg[b + (size_t)(j + 0 + r) * MSGB + c];
            v1 = (float)msg[b + (size_t)(j + 2 + r) * MSGB + c];
            v2 = (float)msg[b + (size_t)(j + 4 + r) * MSGB + c];
            v3 = (float)msg[b + (size_t)(j + 6 + r) * MSGB + c];
        }
        acc += (v0 + v1) + (v2 + v3);
    }
    for (; j + 2 <= deg; j += 2)
        if (c < MSG) acc += (float)msg[b + (size_t)(j + r) * MSGB + c];
    if (j < deg && r == 0 && c < MSG) acc += (float)msg[b + (size_t)j * MSGB + c];

    acc += __shfl_xor(acc, 32);    // combine the two row slots
    if (r == 0 && c < MSG) out[(size_t)n * MSG + c] = acc / fmaxf((float)deg, 1.f);
}

__global__ void finalize_kernel(float* __restrict__ out,
                                const float* __restrict__ cnt, int total)
{
    const int idx = blockIdx.x * blockDim.x + threadIdx.x;
    if (idx < total) {
        const int n = idx / MSG;
        out[idx] = out[idx] / fmaxf(cnt[n], 1.0f);
    }
}

extern "C" void kernel_launch(void* const* d_in, const int* in_sizes, int n_in,
                              void* d_out, int out_size, void* d_ws, size_t ws_size,
                              hipStream_t stream)
{
    const float* node_attr  = (const float*)d_in[0];
    const float* edge_attr  = (const float*)d_in[1];
    const float* edge_sh    = (const float*)d_in[2];
    const float* fc1_w      = (const float*)d_in[3];
    const float* fc1_b      = (const float*)d_in[4];
    const float* fc2_w      = (const float*)d_in[5];
    const float* fc2_b      = (const float*)d_in[6];
    const int*   edge_index = (const int*)d_in[7];

    const int N = in_sizes[0] / NS;
    const int E = in_sizes[1] / NS;
    const int nb = (N + 255) / 256;

    char* ws = (char*)d_ws;
    size_t off = 0;
    auto take = [&](size_t bytes) { off = (off + 255) & ~(size_t)255;
                                    size_t o = off; off += bytes; return o; };
    const size_t o_pk1    = take(PK1_ELEMS * 2);
    const size_t o_pk2    = take(PK2_ELEMS * 2);
    const size_t o_count  = take((size_t)N * 4);
    const size_t o_cursor = take((size_t)N * 4);
    const size_t o_base   = take((size_t)N * 4);
    const size_t o_bsum   = take(1024);
    const size_t o_boff   = take(1024);
    const size_t o_tot    = take(1024);     // scratch bsum-out for 2nd scan (distinct from boff)
    const size_t o_msg    = take((size_t)E * MSGB * 2);
    const bool csr_ok = (off <= ws_size) && (nb <= 256);

    __bf16* pk1 = (__bf16*)(ws + o_pk1);
    __bf16* pk2 = (__bf16*)(ws + o_pk2);
    int* count  = (int*)(ws + o_count);
    float* out  = (float*)d_out;

    const int egrid = (E + 127) / 128;
    const int hblocks = (E + 255) / 256;

    if (csr_ok) {
        int* cursor = (int*)(ws + o_cursor);
        int* base   = (int*)(ws + o_base);
        int* bsum   = (int*)(ws + o_bsum);
        int* boff   = (int*)(ws + o_boff);
        int* tot    = (int*)(ws + o_tot);
        __bf16* msg = (__bf16*)(ws + o_msg);

        // count + cursor are adjacent -> single memset
        hipMemsetAsync(ws + o_count, 0, o_cursor - o_count + (size_t)N * 4, stream);

        prep_kernel<<<PACK_BLOCKS + hblocks, 256, 0, stream>>>(
            fc1_w, fc1_b, fc2_w, fc2_b, edge_index, pk1, pk2, count, E);
        scan_block<<<nb, 256, 0, stream>>>(count, base, bsum, N);
        scan_block<<<1, 256, 0, stream>>>(bsum, boff, tot, nb);

        edge_mfma_kernel<0><<<egrid, 256, 0, stream>>>(node_attr, edge_attr, edge_sh,
                                                       edge_index, base, boff, cursor,
                                                       pk1, pk2, msg, nullptr, nullptr, E);

        node_reduce<<<(N + 3) / 4, 256, 0, stream>>>(msg, count, base, boff, out, N);
    } else {
        float* cntp = (float*)(ws + o_cursor);
        hipMemsetAsync(d_out, 0, (size_t)out_size * sizeof(float), stream);
        hipMemsetAsync(ws + o_count, 0, o_cursor - o_count + (size_t)N * 4, stream);
        prep_kernel<<<PACK_BLOCKS + hblocks, 256, 0, stream>>>(
            fc1_w, fc1_b, fc2_w, fc2_b, edge_index, pk1, pk2, count, E);
        edge_mfma_kernel<1><<<egrid, 256, 0, stream>>>(node_attr, edge_attr, edge_sh,
                                                       edge_index, nullptr, nullptr, nullptr,
                                                       pk1, pk2, nullptr, out, cntp, E);
        const int total = N * MSG;
        finalize_kernel<<<(total + 255) / 256, 256, 0, stream>>>(out, cntp, total);
    }
}

// Round 16
// 122.747 us; speedup vs baseline: 1.1255x; 1.1255x over previous
//
#include <hip/hip_runtime.h>

#define NS   16
#define NV   4
#define FEAT 48          // N_EDGE_FEAT
#define WN   320         // W_NUMEL
#define MSG  28          // logical message width (fp32 out)
#define MSGB 32          // bf16 msg row stride (elements) -> 64 B rows

typedef __bf16 bf16x8 __attribute__((ext_vector_type(8)));
typedef __bf16 bf16x4 __attribute__((ext_vector_type(4)));
typedef float  f32x4  __attribute__((ext_vector_type(4)));

#define PK1_ELEMS (2 * 3 * 64 * 8)    // 3072 bf16
#define PK2_ELEMS (2 * 20 * 64 * 8)   // 20480 bf16
#define PACK_BLOCKS 8

// ---------------- prep: weight packing (blocks 0..7) + histogram WITH positions ----------------
// pos[e] = this edge's arrival index within its src group (the histogram atomic's
// return value, previously discarded). Lets the edge kernel compute its CSR slot
// with plain loads only — zero atomics on the critical kernel (r7<->r9 A/B: the
// inline cursor atomic cost ~15us of edge time).
__global__ void prep_kernel(const float* __restrict__ fc1_w, const float* __restrict__ fc1_b,
                            const float* __restrict__ fc2_w, const float* __restrict__ fc2_b,
                            const int* __restrict__ src,
                            __bf16* __restrict__ pk1, __bf16* __restrict__ pk2,
                            int* __restrict__ count, int* __restrict__ pos, int E)
{
    const int tid = threadIdx.x;
    if (blockIdx.x < PACK_BLOCKS) {
        const int idx = blockIdx.x * 256 + tid;
        const int stride = PACK_BLOCKS * 256;
        for (int i = idx; i < PK1_ELEMS; i += stride) {
            const int j = i & 7, l = (i >> 3) & 63, f = i >> 9;   // f = p*3 + nt
            const int nt = f % 3, p = f / 3;
            const int q = l >> 4, col = 16 * nt + (l & 15);
            float v;
            if (p == 0) {
                const int k = (j < 4) ? (4 * q + j) : (16 + 4 * q + j - 4);
                v = fc1_w[k * FEAT + col];
            } else if (j < 4) {
                v = fc1_w[(32 + 4 * q + j) * FEAT + col];
            } else {
                v = (j == 4 && q == 0) ? fc1_b[col] : 0.f;
            }
            pk1[i] = (__bf16)v;
        }
        for (int i = idx; i < PK2_ELEMS; i += stride) {
            const int j = i & 7, l = (i >> 3) & 63, f = i >> 9;   // f = p*20 + nt
            const int nt = f % 20, p = f / 20;
            const int q = l >> 4, col = 16 * nt + (l & 15);
            float v;
            if (p == 0) {
                const int k = (j < 4) ? (4 * q + j) : (16 + 4 * q + j - 4);
                v = fc2_w[k * WN + col];
            } else if (j < 4) {
                v = fc2_w[(32 + 4 * q + j) * WN + col];
            } else {
                v = (j == 4 && q == 0) ? fc2_b[col] : 0.f;
            }
            pk2[i] = (__bf16)v;
        }
    } else {
        const int nb = gridDim.x - PACK_BLOCKS;
        for (int e = (blockIdx.x - PACK_BLOCKS) * 256 + tid; e < E; e += nb * 256)
            pos[e] = atomicAdd(&count[src[e]], 1);
    }
}

// ---------------- CSR scan ----------------
__global__ void scan_block(const int* __restrict__ in, int* __restrict__ outExcl,
                           int* __restrict__ bsum, int n)
{
    __shared__ int s[256];
    const int tid = threadIdx.x;
    const int i = blockIdx.x * 256 + tid;
    int v = (i < n) ? in[i] : 0;
    int acc = v;
    s[tid] = acc;
    __syncthreads();
    #pragma unroll
    for (int off = 1; off < 256; off <<= 1) {
        int t = (tid >= off) ? s[tid - off] : 0;
        __syncthreads();
        acc += t;
        s[tid] = acc;
        __syncthreads();
    }
    if (i < n) outExcl[i] = acc - v;
    if (tid == 255) bsum[blockIdx.x] = acc;
}

// ---------------- fused edge compute: swapped-operand MFMA, ZERO atomics ----------------
// r12 structure; rank = base[src] + boff[src>>8] + pos[e] — all plain loads (pos
// harvested in prep's histogram). x in wave-private LDS (r6 lesson). (256,7): 36
// VGPR, no spill (r12-verified).
// MODE 0: write bf16 msg row at rank. MODE 1: fp32 atomics into out + cnt.
template<int MODE>
__global__ __launch_bounds__(256, 7) void edge_mfma_kernel(
    const float* __restrict__ node_attr,
    const float* __restrict__ edge_attr,
    const float* __restrict__ edge_sh,
    const int*   __restrict__ edge_index,
    const int*   __restrict__ base,    // MODE 0
    const int*   __restrict__ boff,    // MODE 0
    const int*   __restrict__ pos,     // MODE 0
    const __bf16* __restrict__ pk1,
    const __bf16* __restrict__ pk2,
    __bf16* __restrict__ msg,      // MODE 0
    float*  __restrict__ out_acc,  // MODE 1
    float*  __restrict__ cnt,      // MODE 1
    int E)
{
    __shared__ float sX[4][32][20];    // wave-private; row stride 80 B (16B-aligned)

    const int tid = threadIdx.x;
    const int w   = tid >> 6;
    const int l   = tid & 63;
    const int q   = l >> 4;
    const int r16 = l & 15;
    const int e0  = (blockIdx.x * 4 + w) * 32;    // 32 edges per wave (2 tiles)

    const float4 z4 = make_float4(0.f, 0.f, 0.f, 0.f);
    const float bias1 = (q == 0) ? 1.f : 0.f;

    // fc1 weight frags (register-resident, shared by both tiles)
    bf16x8 w1f[2][3];
    #pragma unroll
    for (int p = 0; p < 2; ++p)
        #pragma unroll
        for (int nt = 0; nt < 3; ++nt)
            w1f[p][nt] = *reinterpret_cast<const bf16x8*>(pk1 + ((size_t)(p * 3 + nt) * 64 + l) * 8);

    // ---- gather ea B-frags (lane supplies feats 4q+j of edge r16); x -> LDS ----
    bf16x8 eaf[2][2];
    int   srcI[2], rnkQ[2];
    bool  evt[2];
    float sh0[2], sh1[2];
    #pragma unroll
    for (int t = 0; t < 2; ++t) {
        const int e = e0 + 16 * t + r16;
        const bool ev = (e < E);
        evt[t] = ev;
        srcI[t] = ev ? edge_index[e] : 0;
        const int dstI = ev ? edge_index[E + e] : 0;

        // CSR slot from plain loads (no atomic): q==0 lanes gather, shfl at write
        rnkQ[t] = 0;
        if (MODE == 0 && q == 0 && ev) {
            const int s = srcI[t];
            rnkQ[t] = base[s] + boff[s >> 8] + pos[e];
        }

        float4 ea4 = z4, sa4 = z4, da4 = z4;
        if (ev) {
            ea4 = *reinterpret_cast<const float4*>(edge_attr + (size_t)e * NS + 4 * q);
            sa4 = *reinterpret_cast<const float4*>(node_attr + (size_t)srcI[t] * NS + 4 * q);
            da4 = *reinterpret_cast<const float4*>(node_attr + (size_t)dstI * NS + 4 * q);
        }
        // lane (q, r16) owns x[4q..4q+3] of edge 16t+r16 -> one b128 LDS write
        *reinterpret_cast<f32x4*>(&sX[w][16 * t + r16][4 * q]) =
            f32x4{da4.x, da4.y, da4.z, da4.w};

        bf16x8 f0, f1;
        f0[0]=(__bf16)ea4.x; f0[1]=(__bf16)ea4.y; f0[2]=(__bf16)ea4.z; f0[3]=(__bf16)ea4.w;
        f0[4]=(__bf16)sa4.x; f0[5]=(__bf16)sa4.y; f0[6]=(__bf16)sa4.z; f0[7]=(__bf16)sa4.w;
        f1[0]=(__bf16)da4.x; f1[1]=(__bf16)da4.y; f1[2]=(__bf16)da4.z; f1[3]=(__bf16)da4.w;
        f1[4]=(__bf16)bias1; f1[5]=(__bf16)0.f; f1[6]=(__bf16)0.f; f1[7]=(__bf16)0.f;
        eaf[t][0] = f0;
        eaf[t][1] = f1;
        sh0[t] = ev ? edge_sh[(size_t)e * 9] : 0.f;
        sh1[t] = (ev && q < 3) ? edge_sh[(size_t)e * 9 + 1 + q] : 0.f;
    }

    // ---- fc1 (swapped): D[row=feat 16nt+4q+g][col=edge r16]; relu; repack to hc frags ----
    bf16x8 hc[2][2];
    #pragma unroll
    for (int t = 0; t < 2; ++t) {
        f32x4 h0 = {0.f,0.f,0.f,0.f}, h1 = {0.f,0.f,0.f,0.f}, h2 = {0.f,0.f,0.f,0.f};
        h0 = __builtin_amdgcn_mfma_f32_16x16x32_bf16(w1f[0][0], eaf[t][0], h0, 0, 0, 0);
        h0 = __builtin_amdgcn_mfma_f32_16x16x32_bf16(w1f[1][0], eaf[t][1], h0, 0, 0, 0);
        h1 = __builtin_amdgcn_mfma_f32_16x16x32_bf16(w1f[0][1], eaf[t][0], h1, 0, 0, 0);
        h1 = __builtin_amdgcn_mfma_f32_16x16x32_bf16(w1f[1][1], eaf[t][1], h1, 0, 0, 0);
        h2 = __builtin_amdgcn_mfma_f32_16x16x32_bf16(w1f[0][2], eaf[t][0], h2, 0, 0, 0);
        h2 = __builtin_amdgcn_mfma_f32_16x16x32_bf16(w1f[1][2], eaf[t][1], h2, 0, 0, 0);
        bf16x8 c0, c1;
        #pragma unroll
        for (int g = 0; g < 4; ++g) {
            c0[g]     = (__bf16)fmaxf(h0[g], 0.f);   // feats  4q+g   (nt=0)
            c0[4 + g] = (__bf16)fmaxf(h1[g], 0.f);   // feats 16+4q+g (nt=1)
            c1[g]     = (__bf16)fmaxf(h2[g], 0.f);   // feats 32+4q+g (nt=2)
        }
        c1[4] = (__bf16)bias1;                       // k=48 constant-1 (bias row)
        c1[5] = (__bf16)0.f; c1[6] = (__bf16)0.f; c1[7] = (__bf16)0.f;
        hc[t][0] = c0;
        hc[t][1] = c1;
    }

    // ---- fc2 (swapped) + fused tensor product (x from wave-private LDS) ----
    f32x4 acc0[2] = {{0.f,0.f,0.f,0.f},{0.f,0.f,0.f,0.f}};
    f32x4 acc1[2] = {{0.f,0.f,0.f,0.f},{0.f,0.f,0.f,0.f}};
    #pragma unroll 4
    for (int nt2 = 0; nt2 < 20; ++nt2) {
        const bf16x8 wf0 = *reinterpret_cast<const bf16x8*>(pk2 + ((size_t)(0 * 20 + nt2) * 64 + l) * 8);
        const bf16x8 wf1 = *reinterpret_cast<const bf16x8*>(pk2 + ((size_t)(1 * 20 + nt2) * 64 + l) * 8);
        #pragma unroll
        for (int t = 0; t < 2; ++t) {
            f32x4 d = {0.f,0.f,0.f,0.f};
            d = __builtin_amdgcn_mfma_f32_16x16x32_bf16(wf0, hc[t][0], d, 0, 0, 0);
            d = __builtin_amdgcn_mfma_f32_16x16x32_bf16(wf1, hc[t][1], d, 0, 0, 0);
            // lane holds w[edge r16][wcol = 16*nt2 + 4q+g]
            if (nt2 < 16) {
                // w0[u=nt2][c=4q+g]
                const float xv = sX[w][16 * t + r16][nt2];
                #pragma unroll
                for (int g = 0; g < 4; ++g) acc0[t][g] = fmaf(xv, d[g], acc0[t][g]);
            } else {
                // w1[u=4*(nt2-16)+q][v=g]
                const float xu = sX[w][16 * t + r16][4 * (nt2 - 16) + q];
                #pragma unroll
                for (int g = 0; g < 4; ++g) acc1[t][g] = fmaf(xu, d[g], acc1[t][g]);
            }
        }
    }

    const float inv = 0.25f;   // 1/sqrt(16)

    // out1: reduce partial u-sums across the 4 q-groups (lane bits 4,5)
    #pragma unroll
    for (int t = 0; t < 2; ++t)
        #pragma unroll
        for (int g = 0; g < 4; ++g) {
            float s = acc1[t][g];
            s += __shfl_xor(s, 16);
            s += __shfl_xor(s, 32);
            acc1[t][g] = s;
        }

    #pragma unroll
    for (int t = 0; t < 2; ++t) {
        const int e = e0 + 16 * t + r16;
        if (e >= E) continue;
        if (MODE == 0) {
            const int rnk = __shfl(rnkQ[t], r16);      // broadcast q==0 lanes' slot
            const size_t mb = (size_t)rnk * MSGB;
            bf16x4 v4;
            #pragma unroll
            for (int g = 0; g < 4; ++g) v4[g] = (__bf16)(inv * sh0[t] * acc0[t][g]);
            *reinterpret_cast<bf16x4*>(msg + mb + 4 * q) = v4;                 // cols 4q..4q+3
            if (q < 3) {
                #pragma unroll
                for (int g = 0; g < 4; ++g)
                    msg[mb + 16 + 3 * g + q] =
                        (__bf16)(inv * sh1[t] * acc1[t][g]);                   // m=q, v=g
            }
        } else {
            const size_t ob = (size_t)srcI[t] * MSG;
            #pragma unroll
            for (int g = 0; g < 4; ++g)
                atomicAdd(&out_acc[ob + 4 * q + g], inv * sh0[t] * acc0[t][g]);
            if (q < 3) {
                #pragma unroll
                for (int g = 0; g < 4; ++g)
                    atomicAdd(&out_acc[ob + 16 + 3 * g + q], inv * sh1[t] * acc1[t][g]);
            }
            if (q == 3) atomicAdd(&cnt[srcI[t]], 1.f);
        }
    }
}

// ---------------- node gather-reduce: contiguous CSR-ordered msg rows ----------------
__global__ __launch_bounds__(256) void node_reduce(
    const __bf16* __restrict__ msg,
    const int* __restrict__ count,
    const int* __restrict__ base,
    const int* __restrict__ boff,
    float* __restrict__ out, int N)
{
    const int tid  = threadIdx.x;
    const int w    = tid >> 6;
    const int l    = tid & 63;
    const int slot = l >> 5;
    const int c    = l & 31;
    const int n    = blockIdx.x * 8 + w * 2 + slot;
    if (n >= N || c >= MSG) return;

    const int deg = count[n];
    const size_t b = (size_t)(base[n] + boff[n >> 8]) * MSGB;
    float acc = 0.f;
    int j = 0;
    for (; j + 4 <= deg; j += 4) {
        const float v0 = (float)msg[b + (size_t)(j + 0) * MSGB + c];
        const float v1 = (float)msg[b + (size_t)(j + 1) * MSGB + c];
        const float v2 = (float)msg[b + (size_t)(j + 2) * MSGB + c];
        const float v3 = (float)msg[b + (size_t)(j + 3) * MSGB + c];
        acc += (v0 + v1) + (v2 + v3);
    }
    for (; j < deg; ++j) acc += (float)msg[b + (size_t)j * MSGB + c];
    out[(size_t)n * MSG + c] = acc / fmaxf((float)deg, 1.f);
}

__global__ void finalize_kernel(float* __restrict__ out,
                                const float* __restrict__ cnt, int total)
{
    const int idx = blockIdx.x * blockDim.x + threadIdx.x;
    if (idx < total) {
        const int n = idx / MSG;
        out[idx] = out[idx] / fmaxf(cnt[n], 1.0f);
    }
}

extern "C" void kernel_launch(void* const* d_in, const int* in_sizes, int n_in,
                              void* d_out, int out_size, void* d_ws, size_t ws_size,
                              hipStream_t stream)
{
    const float* node_attr  = (const float*)d_in[0];
    const float* edge_attr  = (const float*)d_in[1];
    const float* edge_sh    = (const float*)d_in[2];
    const float* fc1_w      = (const float*)d_in[3];
    const float* fc1_b      = (const float*)d_in[4];
    const float* fc2_w      = (const float*)d_in[5];
    const float* fc2_b      = (const float*)d_in[6];
    const int*   edge_index = (const int*)d_in[7];

    const int N = in_sizes[0] / NS;
    const int E = in_sizes[1] / NS;
    const int nb = (N + 255) / 256;

    char* ws = (char*)d_ws;
    size_t off = 0;
    auto take = [&](size_t bytes) { off = (off + 255) & ~(size_t)255;
                                    size_t o = off; off += bytes; return o; };
    const size_t o_pk1    = take(PK1_ELEMS * 2);
    const size_t o_pk2    = take(PK2_ELEMS * 2);
    const size_t o_count  = take((size_t)N * 4);
    const size_t o_base   = take((size_t)N * 4);
    const size_t o_cnt    = take((size_t)N * 4);   // MODE1 fallback only
    const size_t o_bsum   = take(1024);
    const size_t o_boff   = take(1024);
    const size_t o_tot    = take(1024);     // scratch bsum-out for 2nd scan (distinct from boff)
    const size_t o_pos    = take((size_t)E * 4);
    const size_t o_msg    = take((size_t)E * MSGB * 2);
    const bool csr_ok = (off <= ws_size) && (nb <= 256);

    __bf16* pk1 = (__bf16*)(ws + o_pk1);
    __bf16* pk2 = (__bf16*)(ws + o_pk2);
    int* count  = (int*)(ws + o_count);
    int* pos    = (int*)(ws + o_pos);
    float* out  = (float*)d_out;

    const int egrid = (E + 127) / 128;
    const int hblocks = (E + 255) / 256;

    if (csr_ok) {
        int* base   = (int*)(ws + o_base);
        int* bsum   = (int*)(ws + o_bsum);
        int* boff   = (int*)(ws + o_boff);
        int* tot    = (int*)(ws + o_tot);
        __bf16* msg = (__bf16*)(ws + o_msg);

        hipMemsetAsync(count, 0, (size_t)N * 4, stream);

        prep_kernel<<<PACK_BLOCKS + hblocks, 256, 0, stream>>>(
            fc1_w, fc1_b, fc2_w, fc2_b, edge_index, pk1, pk2, count, pos, E);
        scan_block<<<nb, 256, 0, stream>>>(count, base, bsum, N);
        scan_block<<<1, 256, 0, stream>>>(bsum, boff, tot, nb);

        edge_mfma_kernel<0><<<egrid, 256, 0, stream>>>(node_attr, edge_attr, edge_sh,
                                                       edge_index, base, boff, pos,
                                                       pk1, pk2, msg, nullptr, nullptr, E);

        node_reduce<<<(N + 7) / 8, 256, 0, stream>>>(msg, count, base, boff, out, N);
    } else {
        float* cntp = (float*)(ws + o_cnt);
        hipMemsetAsync(d_out, 0, (size_t)out_size * sizeof(float), stream);
        hipMemsetAsync(ws + o_count, 0, (size_t)N * 4, stream);
        hipMemsetAsync(cntp, 0, (size_t)N * 4, stream);
        prep_kernel<<<PACK_BLOCKS + hblocks, 256, 0, stream>>>(
            fc1_w, fc1_b, fc2_w, fc2_b, edge_index, pk1, pk2, count, pos, E);
        edge_mfma_kernel<1><<<egrid, 256, 0, stream>>>(node_attr, edge_attr, edge_sh,
                                                       edge_index, nullptr, nullptr, nullptr,
                                                       pk1, pk2, nullptr, out, cntp, E);
        const int total = N * MSG;
        finalize_kernel<<<(total + 255) / 256, 256, 0, stream>>>(out, cntp, total);
    }
}